// Round 17
// baseline (380.841 us; speedup 1.0000x reference)
//
#include <hip/hip_runtime.h>
#include <hip/hip_bf16.h>

typedef __attribute__((ext_vector_type(8))) short bf16x8;
typedef __attribute__((ext_vector_type(4))) float f32x4;
typedef __attribute__((ext_vector_type(16))) float f32x16;

#define MFMA16(a, b, c) __builtin_amdgcn_mfma_f32_16x16x32_bf16((a), (b), (c), 0, 0, 0)
#define MFMA32(a, b, c) __builtin_amdgcn_mfma_f32_32x32x16_bf16((a), (b), (c), 0, 0, 0)

typedef __attribute__((address_space(1))) const void gconst_t;
typedef __attribute__((address_space(3))) void lds_t;
__device__ __forceinline__ void gload16(const void* gp, void* lp) {
    __builtin_amdgcn_global_load_lds((gconst_t*)gp, (lds_t*)lp, 16, 0, 0);
}

#define BAR() asm volatile("s_barrier" ::: "memory")
#define VMCNT6() asm volatile("s_waitcnt vmcnt(6)" ::: "memory")
#define DRAIN() asm volatile("s_waitcnt vmcnt(0) lgkmcnt(0)" ::: "memory")
#define PRIO1() __builtin_amdgcn_s_setprio(1)
#define PRIO0() __builtin_amdgcn_s_setprio(0)
#define SCHED0() __builtin_amdgcn_sched_barrier(0)

// ---------------------------------------------------------------------------
// Fused prep: z 0..3 -> W[z] 2048x2048 transpose+cast; z 4..7 -> X batch z-4
// (x<32: left, x>=32: right) transpose+cast + raw fp32 copy into concat out;
// block (0,0,4) additionally converts rel_emb -> bf16 padded to 64 rows.
// ---------------------------------------------------------------------------
struct PArgs {
    const float* w[4];
    __hip_bfloat16* wt[4];
    const float* x[2];
    __hip_bfloat16* xb[2];
    const float* rel;
    __hip_bfloat16* relb;
    float* out;
};
__global__ void prep(PArgs pa) {
    __shared__ float tile[32][33];
    const int z = blockIdx.z;
    const int tx = threadIdx.x, ty = threadIdx.y;
    if (z < 4) {
        const float* __restrict__ ib = pa.w[z];
        __hip_bfloat16* __restrict__ ob = pa.wt[z];
        int r0 = blockIdx.y * 32, c0 = blockIdx.x * 32;
#pragma unroll
        for (int i = ty; i < 32; i += 8)
            tile[i][tx] = ib[(size_t)(r0 + i) * 2048 + c0 + tx];
        __syncthreads();
#pragma unroll
        for (int i = ty; i < 32; i += 8)
            ob[(size_t)(c0 + i) * 2048 + r0 + tx] = __float2bfloat16(tile[tx][i]);
    } else {
        const int zb = z - 4;
        const int side = blockIdx.x >> 5;  // 0: left, 1: right
        size_t zoff = (size_t)zb * 2048 * 1024;
        const float* __restrict__ ib = pa.x[side] + zoff;
        __hip_bfloat16* __restrict__ ob = pa.xb[side] + zoff;
        float* __restrict__ cb = pa.out + (size_t)side * 16777216 + (size_t)zb * 4194304;
        int r0 = blockIdx.y * 32, c0 = (blockIdx.x & 31) * 32;
#pragma unroll
        for (int i = ty; i < 32; i += 8) {
            float v = ib[(size_t)(r0 + i) * 1024 + c0 + tx];
            tile[i][tx] = v;
            cb[(size_t)(r0 + i) * 1024 + c0 + tx] = v;
        }
        __syncthreads();
#pragma unroll
        for (int i = ty; i < 32; i += 8)
            ob[(size_t)(c0 + i) * 2048 + r0 + tx] = __float2bfloat16(tile[tx][i]);
        if (z == 4 && blockIdx.x == 0 && blockIdx.y == 0) {
            int tid = ty * 32 + tx;
            for (int i = tid; i < 64 * 256; i += 256) {
                int r = i >> 8;
                pa.relb[i] = __float2bfloat16(r < 63 ? pa.rel[i] : 0.f);
            }
        }
    }
}

// ---------------------------------------------------------------------------
// 256x256 tile, BK=64, 8 waves (2Mx4N, wave tile 128x64), 1 block/CU.
// r16 3-phase quarter-staged counted-vmcnt schedule, MFMA shape switched to
// 32x32x16 (measured pipe: 2495 vs 2176 TF -> ~15% lower compute floor; same
// LDS traffic, same 96-frag/128-acc footprint).  Wave tile = 4 m-frags x
// 2 n-frags of 32x32.  aL=m0,1 / aH=m2,3 / bL=n0 / bH=n1; each [.][ks 0..3].
//   P1: rd aL,bL(C) | ST A-q1,q3(t+1)->C^1           | BAR | MQ(aL·bL)
//   P2: rd bH(C)    | ST A-q0,q2(t+2)->C             | BAR | MQ(aL·bH)
//   P3: rd aH(C)    | ST B-q0..3(t+2)->C | vmcnt(6)  | BAR | MQ(aH·bH); MQ(aH·bL)
// Fragment layout (HW-verified m74/m101 family): A/B lane l -> row/col=l&31,
// k=(l>>5)*8+i; C/D row=(reg&3)+8*(reg>>2)+4*(l>>5), col=l&31.
// LDS byte off = (ks*32 + ((l>>5)<<4)) ^ ((l&7)<<4)  (uniform 8 lanes per
// 4-bank group under the proven XOR swizzle -> conflict-free expected).
// Gate/stage ledger identical to r16 (verified).
// ---------------------------------------------------------------------------
struct GArgs {
    const __hip_bfloat16* A[6];
    const __hip_bfloat16* B[6];
    void* C[6];
    const float* bias[6];
};

template <int MODE>
__global__ __launch_bounds__(512, 2) void gemm8p(GArgs ga, float* __restrict__ dout) {
    constexpr int K = 2048;
    constexpr int NOUT = 2048;
    constexpr int NT = 32;  // K / 64
    __shared__ __align__(16) char smem[131072];

    // XCD-aware chunked swizzle (nwg % 8 == 0 for all our launches)
    const int gx = gridDim.x, gy = gridDim.y;
    int lid = blockIdx.x + gx * (blockIdx.y + gy * blockIdx.z);
    const int nwg = gx * gy * gridDim.z;
    int swz = (lid & 7) * (nwg >> 3) + (lid >> 3);
    const int z = swz / (gx * gy);
    int rem = swz - z * (gx * gy);
    const int by = rem / gx;
    const int bx = rem - by * gx;

    const __hip_bfloat16* __restrict__ A = ga.A[z];
    const __hip_bfloat16* __restrict__ B = ga.B[z];
    const float* __restrict__ bias = ga.bias[z];
    const int row0 = by * 256, col0 = bx * 256;

    const int tid = threadIdx.x;
    const int wave = tid >> 6, lane = tid & 63;
    const int l31 = lane & 31, lh = lane >> 5;
    const int wm = wave >> 2, wn = wave & 3;  // 2x4 grid of 128x64 wave tiles

    // staging: 1 quarter (64 rows x 64K = 8KB) per gload_lds per thread
    const int srow = tid >> 3;               // 0..63 row within quarter
    const int sch = (tid & 7) ^ (srow & 7);  // swizzled source chunk (rule #21)
    // read-side: byte off(ks) = (ks*32 + (lh<<4)) ^ ((l31&7)<<4)
    const int xr = (l31 & 7) << 4;
    const int lhi = lh << 4;

    f32x16 acc[4][2] = {};
    bf16x8 aL[2][4], aH[2][4], bL[4], bH[4];

    // stage one 64-row quarter q of A (isB=0) or B (isB=1) of K-tile T -> buf
    auto STQ = [&](const __hip_bfloat16* base, int rowb, int T, int buf, int isB, int q) {
        gload16(base + (size_t)(rowb + q * 64 + srow) * K + T * 64 + sch * 8,
                smem + buf * 65536 + isB * 32768 + q * 8192 + tid * 16);
    };

#define RD_A(DST, C, MH)                                                              \
    _Pragma("unroll") for (int mf2 = 0; mf2 < 2; ++mf2)                               \
    _Pragma("unroll") for (int ks = 0; ks < 4; ++ks) {                                \
        const char* p =                                                               \
            smem + (C) * 65536 + (wm * 128 + ((MH) * 2 + mf2) * 32 + l31) * 128;      \
        DST[mf2][ks] = *(const bf16x8*)(p + ((ks * 32 + lhi) ^ xr));                  \
    }
#define RD_B(DST, C, NH)                                                              \
    _Pragma("unroll") for (int ks = 0; ks < 4; ++ks) {                                \
        const char* p =                                                               \
            smem + (C) * 65536 + 32768 + (wn * 64 + (NH) * 32 + l31) * 128;           \
        DST[ks] = *(const bf16x8*)(p + ((ks * 32 + lhi) ^ xr));                       \
    }
#define MQ(MH, NH, AR, BR)                                                            \
    SCHED0();                                                                         \
    PRIO1();                                                                          \
    _Pragma("unroll") for (int ks = 0; ks < 4; ++ks)                                  \
    _Pragma("unroll") for (int mf2 = 0; mf2 < 2; ++mf2)                               \
        acc[(MH) * 2 + mf2][(NH)] = MFMA32(AR[mf2][ks], BR[ks], acc[(MH) * 2 + mf2][(NH)]); \
    PRIO0();

#define KTILE(T, C)                                          \
    {                                                        \
        const int tn1 = ((T) + 1 < NT) ? (T) + 1 : (T)-1;    \
        const int tn2 = ((T) + 2 < NT) ? (T) + 2 : (T);      \
        /* P1 */                                             \
        RD_A(aL, C, 0);                                      \
        RD_B(bL, C, 0);                                      \
        STQ(A, row0, tn1, (C) ^ 1, 0, 1);                    \
        STQ(A, row0, tn1, (C) ^ 1, 0, 3);                    \
        BAR();                                               \
        MQ(0, 0, aL, bL);                                    \
        /* P2 */                                             \
        RD_B(bH, C, 1);                                      \
        STQ(A, row0, tn2, (C), 0, 0);                        \
        STQ(A, row0, tn2, (C), 0, 2);                        \
        BAR();                                               \
        MQ(0, 1, aL, bH);                                    \
        /* P3 (merged) */                                    \
        RD_A(aH, C, 1);                                      \
        STQ(B, col0, tn2, (C), 1, 0);                        \
        STQ(B, col0, tn2, (C), 1, 1);                        \
        STQ(B, col0, tn2, (C), 1, 2);                        \
        STQ(B, col0, tn2, (C), 1, 3);                        \
        VMCNT6();                                            \
        BAR();                                               \
        MQ(1, 1, aH, bH);                                    \
        MQ(1, 0, aH, bL);                                    \
    }

    // prologue: t0 full (8 quarters, oldest) + t1 early-6 (A-q0,q2 + B all)
#pragma unroll
    for (int q = 0; q < 4; ++q) {
        STQ(A, row0, 0, 0, 0, q);
        STQ(B, col0, 0, 0, 1, q);
    }
    STQ(A, row0, 1, 1, 0, 0);
    STQ(A, row0, 1, 1, 0, 2);
    STQ(B, col0, 1, 1, 1, 0);
    STQ(B, col0, 1, 1, 1, 1);
    STQ(B, col0, 1, 1, 1, 2);
    STQ(B, col0, 1, 1, 1, 3);
    VMCNT6();  // drains t0's 8; t1's 6 stay in flight
    BAR();

#pragma unroll 1
    for (int t = 0; t < NT; t += 2) {
        KTILE(t, 0);
        KTILE(t + 1, 1);
    }
    DRAIN();  // leftover in-flight stages before epilogue

    if (MODE == 0) {
        __hip_bfloat16* __restrict__ C = (__hip_bfloat16*)ga.C[z];
#pragma unroll
        for (int mf = 0; mf < 4; ++mf) {
#pragma unroll
            for (int nf = 0; nf < 2; ++nf) {
                int n = col0 + wn * 64 + nf * 32 + l31;
                float bv = bias[n];
#pragma unroll
                for (int reg = 0; reg < 16; ++reg) {
                    int m = row0 + wm * 128 + mf * 32 + (reg & 3) + 8 * (reg >> 2) + 4 * lh;
                    C[(size_t)m * NOUT + n] = __float2bfloat16(acc[mf][nf][reg] + bv);
                }
            }
        }
    } else {
        // A rows = output channel n; B rows = m = b*1024 + p (coalesced in p)
        float* __restrict__ OB = dout + (size_t)z * 16777216;
#pragma unroll
        for (int mf = 0; mf < 4; ++mf) {
#pragma unroll
            for (int nf = 0; nf < 2; ++nf) {
                int m = col0 + wn * 64 + nf * 32 + l31;
                size_t base = (size_t)(m >> 10) * 4194304 + (size_t)(m & 1023);
#pragma unroll
                for (int reg = 0; reg < 16; ++reg) {
                    int n = row0 + wm * 128 + mf * 32 + (reg & 3) + 8 * (reg >> 2) + 4 * lh;
                    OB[base + (size_t)(2048 + n) * 1024] = acc[mf][nf][reg] + bias[n];
                }
            }
        }
    }
#undef RD_A
#undef RD_B
#undef MQ
#undef KTILE
}

// ---------------------------------------------------------------------------
// Axial attention: one block per (dir, b, head, w).  Q,K,V row-major [4096][2048] bf16.
// ---------------------------------------------------------------------------
__global__ __launch_bounds__(256, 2) void attn_kernel(
    const __hip_bfloat16* __restrict__ Qa, const __hip_bfloat16* __restrict__ Ka,
    const __hip_bfloat16* __restrict__ Va, const __hip_bfloat16* __restrict__ Qb,
    const __hip_bfloat16* __restrict__ Kb, const __hip_bfloat16* __restrict__ Vb,
    const __hip_bfloat16* __restrict__ relb, __hip_bfloat16* __restrict__ Oa,
    __hip_bfloat16* __restrict__ Ob) {
    const int w = blockIdx.x;   // 0..31
    const int nh = blockIdx.y;  // 0..7
    const int zb = blockIdx.z;  // dir*4 + b
    const int dir = zb >> 2, b = zb & 3;
    const __hip_bfloat16* __restrict__ Q = dir ? Qb : Qa;
    const __hip_bfloat16* __restrict__ K = dir ? Kb : Ka;
    const __hip_bfloat16* __restrict__ V = dir ? Vb : Va;
    __hip_bfloat16* __restrict__ O = dir ? Ob : Oa;

    __shared__ __align__(16) __hip_bfloat16 vt[256 * 40];  // V^T, stride 40
    __shared__ float ssc[32 * 32];
    __shared__ float es[32 * 64];
    __shared__ __align__(16) __hip_bfloat16 ps[32 * 32];

    const int tid = threadIdx.x;
    const int lane = tid & 63, wave = tid >> 6;
    const int l15 = lane & 15, lg = lane >> 4;
    const int mt = wave >> 1, nt = wave & 1;

    const size_t rowbase = ((size_t)b * 1024 + w) * 2048 + (size_t)nh * 256;

    // stage V transposed: vt[c][hk]
    for (int i = 0; i < 32; ++i) {
        int e = i * 256 + tid;
        int hk = e >> 8, c = e & 255;
        vt[c * 40 + hk] = V[rowbase + (size_t)hk * 65536 + c];
    }

    f32x4 sacc = {}, e0 = {}, e1 = {};
#pragma unroll
    for (int k8 = 0; k8 < 256; k8 += 32) {
        bf16x8 af = *(const bf16x8*)&Q[rowbase + (size_t)(mt * 16 + l15) * 65536 + k8 + lg * 8];
        bf16x8 bf = *(const bf16x8*)&K[rowbase + (size_t)(nt * 16 + l15) * 65536 + k8 + lg * 8];
        bf16x8 r0 = *(const bf16x8*)&relb[(size_t)(nt * 32 + l15) * 256 + k8 + lg * 8];
        bf16x8 r1 = *(const bf16x8*)&relb[(size_t)(nt * 32 + 16 + l15) * 256 + k8 + lg * 8];
        sacc = MFMA16(af, bf, sacc);
        e0 = MFMA16(af, r0, e0);
        e1 = MFMA16(af, r1, e1);
    }
#pragma unroll
    for (int r = 0; r < 4; ++r) {
        int row = mt * 16 + lg * 4 + r;
        ssc[row * 32 + nt * 16 + l15] = sacc[r];
        es[row * 64 + nt * 32 + l15] = e0[r];
        es[row * 64 + nt * 32 + 16 + l15] = e1[r];
    }
    __syncthreads();

    {
        int h = tid >> 3, sub = tid & 7;
        float v4[4];
        float mx = -1e30f;
#pragma unroll
        for (int i = 0; i < 4; ++i) {
            int k = sub * 4 + i;
            int dh = k - h; if (dh < 0) dh += 63;
            int dw = k - w; if (dw < 0) dw += 63;
            float s = (ssc[h * 32 + k] + es[h * 64 + dh] + es[h * 64 + dw]) * 0.0625f;
            v4[i] = s;
            mx = fmaxf(mx, s);
        }
        mx = fmaxf(mx, __shfl_xor(mx, 1));
        mx = fmaxf(mx, __shfl_xor(mx, 2));
        mx = fmaxf(mx, __shfl_xor(mx, 4));
        float sum = 0.f;
#pragma unroll
        for (int i = 0; i < 4; ++i) {
            v4[i] = __expf(v4[i] - mx);
            sum += v4[i];
        }
        sum += __shfl_xor(sum, 1);
        sum += __shfl_xor(sum, 2);
        sum += __shfl_xor(sum, 4);
        float inv = 1.f / sum;
#pragma unroll
        for (int i = 0; i < 4; ++i) ps[h * 32 + sub * 4 + i] = __float2bfloat16(v4[i] * inv);
    }
    __syncthreads();

    bf16x8 paf = *(const bf16x8*)&ps[(mt * 16 + l15) * 32 + lg * 8];
#pragma unroll
    for (int j = 0; j < 8; ++j) {
        int ct = nt * 8 + j;  // 0..15
        bf16x8 bv = *(const bf16x8*)&vt[(size_t)(ct * 16 + l15) * 40 + lg * 8];
        f32x4 oacc = {};
        oacc = MFMA16(paf, bv, oacc);
#pragma unroll
        for (int r = 0; r < 4; ++r) {
            int hh = mt * 16 + lg * 4 + r;
            O[rowbase + (size_t)hh * 65536 + ct * 16 + l15] = __float2bfloat16(oacc[r]);
        }
    }
}

// ---------------------------------------------------------------------------
extern "C" void kernel_launch(void* const* d_in, const int* in_sizes, int n_in, void* d_out,
                              int out_size, void* d_ws, size_t ws_size, hipStream_t stream) {
    const float* Xl = (const float*)d_in[0];
    const float* Xr = (const float*)d_in[1];
    const float* Wq = (const float*)d_in[2];
    const float* bq = (const float*)d_in[3];
    const float* Wk = (const float*)d_in[4];
    const float* bk = (const float*)d_in[5];
    const float* Wv = (const float*)d_in[6];
    const float* bv = (const float*)d_in[7];
    const float* Wo = (const float*)d_in[8];
    const float* bo = (const float*)d_in[9];
    const float* rel = (const float*)d_in[10];
    float* out = (float*)d_out;

    char* ws = (char*)d_ws;
    size_t off = 0;
    auto nxt = [&](size_t bytes) {
        void* p = ws + off;
        off += bytes;
        return p;
    };
    __hip_bfloat16* Xbl = (__hip_bfloat16*)nxt(16777216);
    __hip_bfloat16* Xbr = (__hip_bfloat16*)nxt(16777216);
    __hip_bfloat16* Wtq = (__hip_bfloat16*)nxt(8388608);
    __hip_bfloat16* Wtk = (__hip_bfloat16*)nxt(8388608);
    __hip_bfloat16* Wtv = (__hip_bfloat16*)nxt(8388608);
    __hip_bfloat16* Wto = (__hip_bfloat16*)nxt(8388608);
    __hip_bfloat16* relb = (__hip_bfloat16*)nxt(32768);
    __hip_bfloat16* Ql = (__hip_bfloat16*)nxt(16777216);
    __hip_bfloat16* Kl = (__hip_bfloat16*)nxt(16777216);
    __hip_bfloat16* Vl = (__hip_bfloat16*)nxt(16777216);
    __hip_bfloat16* Qr = (__hip_bfloat16*)nxt(16777216);
    __hip_bfloat16* Kr = (__hip_bfloat16*)nxt(16777216);
    __hip_bfloat16* Vr = (__hip_bfloat16*)nxt(16777216);
    // att outputs alias the Xb buffers (Xb dead after phase-1 GEMM)
    __hip_bfloat16* At0 = Xbl;
    __hip_bfloat16* At1 = Xbr;

    // fused prep: W transposes (z0-3), X transposes + raw copy (z4-7), rel
    PArgs pa;
    pa.w[0] = Wq; pa.w[1] = Wk; pa.w[2] = Wv; pa.w[3] = Wo;
    pa.wt[0] = Wtq; pa.wt[1] = Wtk; pa.wt[2] = Wtv; pa.wt[3] = Wto;
    pa.x[0] = Xl; pa.x[1] = Xr;
    pa.xb[0] = Xbl; pa.xb[1] = Xbr;
    pa.rel = rel; pa.relb = relb; pa.out = out;
    prep<<<dim3(64, 64, 8), dim3(32, 8), 0, stream>>>(pa);

    GArgs g1 = {};
    g1.A[0] = Xbl; g1.A[1] = Xbl; g1.A[2] = Xbl;
    g1.A[3] = Xbr; g1.A[4] = Xbr; g1.A[5] = Xbr;
    g1.B[0] = Wtq; g1.B[1] = Wtk; g1.B[2] = Wtv;
    g1.B[3] = Wtq; g1.B[4] = Wtk; g1.B[5] = Wtv;
    g1.C[0] = Ql; g1.C[1] = Kl; g1.C[2] = Vl;
    g1.C[3] = Qr; g1.C[4] = Kr; g1.C[5] = Vr;
    g1.bias[0] = bq; g1.bias[1] = bk; g1.bias[2] = bv;
    g1.bias[3] = bq; g1.bias[4] = bk; g1.bias[5] = bv;
    // M=4096/256=16, N=2048/256=8, z=6 -> 768 blocks (3 rounds at 1/CU)
    gemm8p<0><<<dim3(8, 16, 6), 512, 0, stream>>>(g1, nullptr);

    // dir0: weighted_r = attn(Q_l, K_r, V_r); dir1: weighted_l = attn(Q_r, K_l, V_l)
    attn_kernel<<<dim3(32, 8, 8), 256, 0, stream>>>(Ql, Kr, Vr, Qr, Kl, Vl, relb, At0, At1);

    // phase-2: A=Wo^T (2048/256=8 row-blocks), B=att (4096/256=16)
    GArgs g2 = {};
    g2.A[0] = Wto; g2.A[1] = Wto;
    g2.B[0] = At0; g2.B[1] = At1;
    g2.bias[0] = bo; g2.bias[1] = bo;
    gemm8p<1><<<dim3(16, 8, 2), 512, 0, stream>>>(g2, out);
}

// Round 18
// 344.063 us; speedup vs baseline: 1.1069x; 1.1069x over previous
//
#include <hip/hip_runtime.h>
#include <hip/hip_bf16.h>

typedef __attribute__((ext_vector_type(8))) short bf16x8;
typedef __attribute__((ext_vector_type(4))) float f32x4;

#define MFMA16(a, b, c) __builtin_amdgcn_mfma_f32_16x16x32_bf16((a), (b), (c), 0, 0, 0)

typedef __attribute__((address_space(1))) const void gconst_t;
typedef __attribute__((address_space(3))) void lds_t;
__device__ __forceinline__ void gload16(const void* gp, void* lp) {
    __builtin_amdgcn_global_load_lds((gconst_t*)gp, (lds_t*)lp, 16, 0, 0);
}

#define BAR() asm volatile("s_barrier" ::: "memory")
#define VMCNT6() asm volatile("s_waitcnt vmcnt(6)" ::: "memory")
#define DRAIN() asm volatile("s_waitcnt vmcnt(0) lgkmcnt(0)" ::: "memory")
#define PRIO1() __builtin_amdgcn_s_setprio(1)
#define PRIO0() __builtin_amdgcn_s_setprio(0)
#define SCHED0() __builtin_amdgcn_sched_barrier(0)

// ---------------------------------------------------------------------------
// Fused prep: z 0..3 -> W[z] 2048x2048 transpose+cast; z 4..7 -> X batch z-4
// (x<32: left, x>=32: right) transpose+cast + raw fp32 copy into concat out;
// block (0,0,4) additionally converts rel_emb -> bf16 padded to 64 rows.
// ---------------------------------------------------------------------------
struct PArgs {
    const float* w[4];
    __hip_bfloat16* wt[4];
    const float* x[2];
    __hip_bfloat16* xb[2];
    const float* rel;
    __hip_bfloat16* relb;
    float* out;
};
__global__ void prep(PArgs pa) {
    __shared__ float tile[32][33];
    const int z = blockIdx.z;
    const int tx = threadIdx.x, ty = threadIdx.y;
    if (z < 4) {
        const float* __restrict__ ib = pa.w[z];
        __hip_bfloat16* __restrict__ ob = pa.wt[z];
        int r0 = blockIdx.y * 32, c0 = blockIdx.x * 32;
#pragma unroll
        for (int i = ty; i < 32; i += 8)
            tile[i][tx] = ib[(size_t)(r0 + i) * 2048 + c0 + tx];
        __syncthreads();
#pragma unroll
        for (int i = ty; i < 32; i += 8)
            ob[(size_t)(c0 + i) * 2048 + r0 + tx] = __float2bfloat16(tile[tx][i]);
    } else {
        const int zb = z - 4;
        const int side = blockIdx.x >> 5;  // 0: left, 1: right
        size_t zoff = (size_t)zb * 2048 * 1024;
        const float* __restrict__ ib = pa.x[side] + zoff;
        __hip_bfloat16* __restrict__ ob = pa.xb[side] + zoff;
        float* __restrict__ cb = pa.out + (size_t)side * 16777216 + (size_t)zb * 4194304;
        int r0 = blockIdx.y * 32, c0 = (blockIdx.x & 31) * 32;
#pragma unroll
        for (int i = ty; i < 32; i += 8) {
            float v = ib[(size_t)(r0 + i) * 1024 + c0 + tx];
            tile[i][tx] = v;
            cb[(size_t)(r0 + i) * 1024 + c0 + tx] = v;
        }
        __syncthreads();
#pragma unroll
        for (int i = ty; i < 32; i += 8)
            ob[(size_t)(c0 + i) * 2048 + r0 + tx] = __float2bfloat16(tile[tx][i]);
        if (z == 4 && blockIdx.x == 0 && blockIdx.y == 0) {
            int tid = ty * 32 + tx;
            for (int i = tid; i < 64 * 256; i += 256) {
                int r = i >> 8;
                pa.relb[i] = __float2bfloat16(r < 63 ? pa.rel[i] : 0.f);
            }
        }
    }
}

// ---------------------------------------------------------------------------
// 256x256 tile, BK=64, 8 waves (2Mx4N, wave tile 128x64), 1 block/CU.
// Round-15 quarter-staged counted-vmcnt schedule (best measured: 344.2us
// total, phase-1 171us, MfmaUtil 56%, 0 conflicts, no spill):
//   P1: rd aL,bL(C) | ST A-q1,q3(t+1)->C^1 | BAR | MQ(aL·bL)
//   P2: rd bH(C)    | ST A-q0,q2(t+2)->C   | BAR | MQ(aL·bH)
//   P3: rd aH(C)    | ST B-q0,q1(t+2)->C   | BAR | MQ(aH·bH)
//   P4: ST B-q2,q3(t+2)->C | vmcnt(6) | BAR | MQ(aH·bL)
// Gate ledger: at P4, in flight = t+1:{A-q1,q3} + t+2:{6}; vmcnt(6) drains
// all of t+1, leaves t+2's 6 riding the barrier (T4 counted gate).
// Quarter = 64 rows x 64 K = 1 gload_lds/thread; quarters map 1:1 to read
// sets.  16x16x32 MFMA + l15-based XOR swizzle = proven zero-conflict
// (32x32 shape regressed: r17, 1.9e7 conflicts from l31-row aliasing).
// ---------------------------------------------------------------------------
struct GArgs {
    const __hip_bfloat16* A[6];
    const __hip_bfloat16* B[6];
    void* C[6];
    const float* bias[6];
};

template <int MODE>
__global__ __launch_bounds__(512, 2) void gemm8p(GArgs ga, float* __restrict__ dout) {
    constexpr int K = 2048;
    constexpr int NOUT = 2048;
    constexpr int NT = 32;  // K / 64
    __shared__ __align__(16) char smem[131072];

    // XCD-aware chunked swizzle (nwg % 8 == 0 for all our launches)
    const int gx = gridDim.x, gy = gridDim.y;
    int lid = blockIdx.x + gx * (blockIdx.y + gy * blockIdx.z);
    const int nwg = gx * gy * gridDim.z;
    int swz = (lid & 7) * (nwg >> 3) + (lid >> 3);
    const int z = swz / (gx * gy);
    int rem = swz - z * (gx * gy);
    const int by = rem / gx;
    const int bx = rem - by * gx;

    const __hip_bfloat16* __restrict__ A = ga.A[z];
    const __hip_bfloat16* __restrict__ B = ga.B[z];
    const float* __restrict__ bias = ga.bias[z];
    const int row0 = by * 256, col0 = bx * 256;

    const int tid = threadIdx.x;
    const int wave = tid >> 6, lane = tid & 63;
    const int l15 = lane & 15, lg = lane >> 4;
    const int wm = wave >> 2, wn = wave & 3;  // 2x4 grid of 128x64 wave tiles

    // staging: 1 quarter (64 rows x 64K = 8KB) per gload_lds per thread
    const int srow = tid >> 3;               // 0..63 row within quarter
    const int sch = (tid & 7) ^ (srow & 7);  // swizzled source chunk (rule #21)
    // read-side XOR (proven zero-conflict layout)
    const int xr = (l15 & 7) << 4;
    const int off0 = (lg * 16) ^ xr;
    const int off1 = (64 + lg * 16) ^ xr;

    f32x4 acc[8][4] = {};
    bf16x8 aL[4][2], aH[4][2], bL[2][2], bH[2][2];

    // stage one 64-row quarter q of A (isB=0) or B (isB=1) of K-tile T -> buf
    auto STQ = [&](const __hip_bfloat16* base, int rowb, int T, int buf, int isB, int q) {
        gload16(base + (size_t)(rowb + q * 64 + srow) * K + T * 64 + sch * 8,
                smem + buf * 65536 + isB * 32768 + q * 8192 + tid * 16);
    };

#define RD_A(DST, C, MH)                                                           \
    _Pragma("unroll") for (int mf = 0; mf < 4; ++mf) {                             \
        const char* p = smem + (C) * 65536 + (wm * 128 + (MH) * 64 + mf * 16 + l15) * 128; \
        DST[mf][0] = *(const bf16x8*)(p + off0);                                   \
        DST[mf][1] = *(const bf16x8*)(p + off1);                                   \
    }
#define RD_B(DST, C, NH)                                                           \
    _Pragma("unroll") for (int nf = 0; nf < 2; ++nf) {                             \
        const char* p = smem + (C) * 65536 + 32768 +                               \
                        (wn * 64 + (NH) * 32 + nf * 16 + l15) * 128;               \
        DST[nf][0] = *(const bf16x8*)(p + off0);                                   \
        DST[nf][1] = *(const bf16x8*)(p + off1);                                   \
    }
#define MQ(MH, NH, AR, BR)                                                         \
    SCHED0();                                                                      \
    PRIO1();                                                                       \
    _Pragma("unroll") for (int mf = 0; mf < 4; ++mf)                               \
    _Pragma("unroll") for (int nf = 0; nf < 2; ++nf) {                             \
        acc[(MH)*4 + mf][(NH)*2 + nf] =                                            \
            MFMA16(AR[mf][0], BR[nf][0], acc[(MH)*4 + mf][(NH)*2 + nf]);           \
        acc[(MH)*4 + mf][(NH)*2 + nf] =                                            \
            MFMA16(AR[mf][1], BR[nf][1], acc[(MH)*4 + mf][(NH)*2 + nf]);           \
    }                                                                              \
    PRIO0();

#define KTILE(T, C)                                          \
    {                                                        \
        const int tn1 = ((T) + 1 < NT) ? (T) + 1 : (T)-1;    \
        const int tn2 = ((T) + 2 < NT) ? (T) + 2 : (T);      \
        /* P1 */                                             \
        RD_A(aL, C, 0);                                      \
        RD_B(bL, C, 0);                                      \
        STQ(A, row0, tn1, (C) ^ 1, 0, 1);                    \
        STQ(A, row0, tn1, (C) ^ 1, 0, 3);                    \
        BAR();                                               \
        MQ(0, 0, aL, bL);                                    \
        /* P2 */                                             \
        RD_B(bH, C, 1);                                      \
        STQ(A, row0, tn2, (C), 0, 0);                        \
        STQ(A, row0, tn2, (C), 0, 2);                        \
        BAR();                                               \
        MQ(0, 1, aL, bH);                                    \
        /* P3 */                                             \
        RD_A(aH, C, 1);                                      \
        STQ(B, col0, tn2, (C), 1, 0);                        \
        STQ(B, col0, tn2, (C), 1, 1);                        \
        BAR();                                               \
        MQ(1, 1, aH, bH);                                    \
        /* P4 */                                             \
        STQ(B, col0, tn2, (C), 1, 2);                        \
        STQ(B, col0, tn2, (C), 1, 3);                        \
        VMCNT6();                                            \
        BAR();                                               \
        MQ(1, 0, aH, bL);                                    \
    }

    // prologue: t0 full (8 quarters, oldest) + t1 early-6 (A-q0,q2 + B all)
#pragma unroll
    for (int q = 0; q < 4; ++q) {
        STQ(A, row0, 0, 0, 0, q);
        STQ(B, col0, 0, 0, 1, q);
    }
    STQ(A, row0, 1, 1, 0, 0);
    STQ(A, row0, 1, 1, 0, 2);
    STQ(B, col0, 1, 1, 1, 0);
    STQ(B, col0, 1, 1, 1, 1);
    STQ(B, col0, 1, 1, 1, 2);
    STQ(B, col0, 1, 1, 1, 3);
    VMCNT6();  // drains t0's 8; t1's 6 stay in flight
    BAR();

#pragma unroll 1
    for (int t = 0; t < NT; t += 2) {
        KTILE(t, 0);
        KTILE(t + 1, 1);
    }
    DRAIN();  // leftover in-flight stages before epilogue

    if (MODE == 0) {
        __hip_bfloat16* __restrict__ C = (__hip_bfloat16*)ga.C[z];
#pragma unroll
        for (int mf = 0; mf < 8; ++mf) {
            int m = row0 + wm * 128 + mf * 16 + lg * 4;
#pragma unroll
            for (int nf = 0; nf < 4; ++nf) {
                int n = col0 + wn * 64 + nf * 16 + l15;
                float bv = bias[n];
#pragma unroll
                for (int r = 0; r < 4; ++r)
                    C[(size_t)(m + r) * NOUT + n] = __float2bfloat16(acc[mf][nf][r] + bv);
            }
        }
    } else {
        // rows = output channel n, cols = m = b*1024 + p (coalesced in p)
        float* __restrict__ OB = dout + (size_t)z * 16777216;
#pragma unroll
        for (int mf = 0; mf < 8; ++mf) {
            int n0 = row0 + wm * 128 + mf * 16 + lg * 4;
#pragma unroll
            for (int nf = 0; nf < 4; ++nf) {
                int m = col0 + wn * 64 + nf * 16 + l15;
                size_t base = (size_t)(m >> 10) * 4194304 + (size_t)(m & 1023);
#pragma unroll
                for (int r = 0; r < 4; ++r) {
                    int n = n0 + r;
                    OB[base + (size_t)(2048 + n) * 1024] = acc[mf][nf][r] + bias[n];
                }
            }
        }
    }
#undef RD_A
#undef RD_B
#undef MQ
#undef KTILE
}

// ---------------------------------------------------------------------------
// Axial attention: one block per (dir, b, head, w).  Q,K,V row-major [4096][2048] bf16.
// ---------------------------------------------------------------------------
__global__ __launch_bounds__(256, 2) void attn_kernel(
    const __hip_bfloat16* __restrict__ Qa, const __hip_bfloat16* __restrict__ Ka,
    const __hip_bfloat16* __restrict__ Va, const __hip_bfloat16* __restrict__ Qb,
    const __hip_bfloat16* __restrict__ Kb, const __hip_bfloat16* __restrict__ Vb,
    const __hip_bfloat16* __restrict__ relb, __hip_bfloat16* __restrict__ Oa,
    __hip_bfloat16* __restrict__ Ob) {
    const int w = blockIdx.x;   // 0..31
    const int nh = blockIdx.y;  // 0..7
    const int zb = blockIdx.z;  // dir*4 + b
    const int dir = zb >> 2, b = zb & 3;
    const __hip_bfloat16* __restrict__ Q = dir ? Qb : Qa;
    const __hip_bfloat16* __restrict__ K = dir ? Kb : Ka;
    const __hip_bfloat16* __restrict__ V = dir ? Vb : Va;
    __hip_bfloat16* __restrict__ O = dir ? Ob : Oa;

    __shared__ __align__(16) __hip_bfloat16 vt[256 * 40];  // V^T, stride 40
    __shared__ float ssc[32 * 32];
    __shared__ float es[32 * 64];
    __shared__ __align__(16) __hip_bfloat16 ps[32 * 32];

    const int tid = threadIdx.x;
    const int lane = tid & 63, wave = tid >> 6;
    const int l15 = lane & 15, lg = lane >> 4;
    const int mt = wave >> 1, nt = wave & 1;

    const size_t rowbase = ((size_t)b * 1024 + w) * 2048 + (size_t)nh * 256;

    // stage V transposed: vt[c][hk]
    for (int i = 0; i < 32; ++i) {
        int e = i * 256 + tid;
        int hk = e >> 8, c = e & 255;
        vt[c * 40 + hk] = V[rowbase + (size_t)hk * 65536 + c];
    }

    f32x4 sacc = {}, e0 = {}, e1 = {};
#pragma unroll
    for (int k8 = 0; k8 < 256; k8 += 32) {
        bf16x8 af = *(const bf16x8*)&Q[rowbase + (size_t)(mt * 16 + l15) * 65536 + k8 + lg * 8];
        bf16x8 bf = *(const bf16x8*)&K[rowbase + (size_t)(nt * 16 + l15) * 65536 + k8 + lg * 8];
        bf16x8 r0 = *(const bf16x8*)&relb[(size_t)(nt * 32 + l15) * 256 + k8 + lg * 8];
        bf16x8 r1 = *(const bf16x8*)&relb[(size_t)(nt * 32 + 16 + l15) * 256 + k8 + lg * 8];
        sacc = MFMA16(af, bf, sacc);
        e0 = MFMA16(af, r0, e0);
        e1 = MFMA16(af, r1, e1);
    }
#pragma unroll
    for (int r = 0; r < 4; ++r) {
        int row = mt * 16 + lg * 4 + r;
        ssc[row * 32 + nt * 16 + l15] = sacc[r];
        es[row * 64 + nt * 32 + l15] = e0[r];
        es[row * 64 + nt * 32 + 16 + l15] = e1[r];
    }
    __syncthreads();

    {
        int h = tid >> 3, sub = tid & 7;
        float v4[4];
        float mx = -1e30f;
#pragma unroll
        for (int i = 0; i < 4; ++i) {
            int k = sub * 4 + i;
            int dh = k - h; if (dh < 0) dh += 63;
            int dw = k - w; if (dw < 0) dw += 63;
            float s = (ssc[h * 32 + k] + es[h * 64 + dh] + es[h * 64 + dw]) * 0.0625f;
            v4[i] = s;
            mx = fmaxf(mx, s);
        }
        mx = fmaxf(mx, __shfl_xor(mx, 1));
        mx = fmaxf(mx, __shfl_xor(mx, 2));
        mx = fmaxf(mx, __shfl_xor(mx, 4));
        float sum = 0.f;
#pragma unroll
        for (int i = 0; i < 4; ++i) {
            v4[i] = __expf(v4[i] - mx);
            sum += v4[i];
        }
        sum += __shfl_xor(sum, 1);
        sum += __shfl_xor(sum, 2);
        sum += __shfl_xor(sum, 4);
        float inv = 1.f / sum;
#pragma unroll
        for (int i = 0; i < 4; ++i) ps[h * 32 + sub * 4 + i] = __float2bfloat16(v4[i] * inv);
    }
    __syncthreads();

    bf16x8 paf = *(const bf16x8*)&ps[(mt * 16 + l15) * 32 + lg * 8];
#pragma unroll
    for (int j = 0; j < 8; ++j) {
        int ct = nt * 8 + j;  // 0..15
        bf16x8 bv = *(const bf16x8*)&vt[(size_t)(ct * 16 + l15) * 40 + lg * 8];
        f32x4 oacc = {};
        oacc = MFMA16(paf, bv, oacc);
#pragma unroll
        for (int r = 0; r < 4; ++r) {
            int hh = mt * 16 + lg * 4 + r;
            O[rowbase + (size_t)hh * 65536 + ct * 16 + l15] = __float2bfloat16(oacc[r]);
        }
    }
}

// ---------------------------------------------------------------------------
extern "C" void kernel_launch(void* const* d_in, const int* in_sizes, int n_in, void* d_out,
                              int out_size, void* d_ws, size_t ws_size, hipStream_t stream) {
    const float* Xl = (const float*)d_in[0];
    const float* Xr = (const float*)d_in[1];
    const float* Wq = (const float*)d_in[2];
    const float* bq = (const float*)d_in[3];
    const float* Wk = (const float*)d_in[4];
    const float* bk = (const float*)d_in[5];
    const float* Wv = (const float*)d_in[6];
    const float* bv = (const float*)d_in[7];
    const float* Wo = (const float*)d_in[8];
    const float* bo = (const float*)d_in[9];
    const float* rel = (const float*)d_in[10];
    float* out = (float*)d_out;

    char* ws = (char*)d_ws;
    size_t off = 0;
    auto nxt = [&](size_t bytes) {
        void* p = ws + off;
        off += bytes;
        return p;
    };
    __hip_bfloat16* Xbl = (__hip_bfloat16*)nxt(16777216);
    __hip_bfloat16* Xbr = (__hip_bfloat16*)nxt(16777216);
    __hip_bfloat16* Wtq = (__hip_bfloat16*)nxt(8388608);
    __hip_bfloat16* Wtk = (__hip_bfloat16*)nxt(8388608);
    __hip_bfloat16* Wtv = (__hip_bfloat16*)nxt(8388608);
    __hip_bfloat16* Wto = (__hip_bfloat16*)nxt(8388608);
    __hip_bfloat16* relb = (__hip_bfloat16*)nxt(32768);
    __hip_bfloat16* Ql = (__hip_bfloat16*)nxt(16777216);
    __hip_bfloat16* Kl = (__hip_bfloat16*)nxt(16777216);
    __hip_bfloat16* Vl = (__hip_bfloat16*)nxt(16777216);
    __hip_bfloat16* Qr = (__hip_bfloat16*)nxt(16777216);
    __hip_bfloat16* Kr = (__hip_bfloat16*)nxt(16777216);
    __hip_bfloat16* Vr = (__hip_bfloat16*)nxt(16777216);
    // att outputs alias the Xb buffers (Xb dead after phase-1 GEMM)
    __hip_bfloat16* At0 = Xbl;
    __hip_bfloat16* At1 = Xbr;

    // fused prep: W transposes (z0-3), X transposes + raw copy (z4-7), rel
    PArgs pa;
    pa.w[0] = Wq; pa.w[1] = Wk; pa.w[2] = Wv; pa.w[3] = Wo;
    pa.wt[0] = Wtq; pa.wt[1] = Wtk; pa.wt[2] = Wtv; pa.wt[3] = Wto;
    pa.x[0] = Xl; pa.x[1] = Xr;
    pa.xb[0] = Xbl; pa.xb[1] = Xbr;
    pa.rel = rel; pa.relb = relb; pa.out = out;
    prep<<<dim3(64, 64, 8), dim3(32, 8), 0, stream>>>(pa);

    GArgs g1 = {};
    g1.A[0] = Xbl; g1.A[1] = Xbl; g1.A[2] = Xbl;
    g1.A[3] = Xbr; g1.A[4] = Xbr; g1.A[5] = Xbr;
    g1.B[0] = Wtq; g1.B[1] = Wtk; g1.B[2] = Wtv;
    g1.B[3] = Wtq; g1.B[4] = Wtk; g1.B[5] = Wtv;
    g1.C[0] = Ql; g1.C[1] = Kl; g1.C[2] = Vl;
    g1.C[3] = Qr; g1.C[4] = Kr; g1.C[5] = Vr;
    g1.bias[0] = bq; g1.bias[1] = bk; g1.bias[2] = bv;
    g1.bias[3] = bq; g1.bias[4] = bk; g1.bias[5] = bv;
    // M=4096/256=16, N=2048/256=8, z=6 -> 768 blocks (3 rounds at 1/CU)
    gemm8p<0><<<dim3(8, 16, 6), 512, 0, stream>>>(g1, nullptr);

    // dir0: weighted_r = attn(Q_l, K_r, V_r); dir1: weighted_l = attn(Q_r, K_l, V_l)
    attn_kernel<<<dim3(32, 8, 8), 256, 0, stream>>>(Ql, Kr, Vr, Qr, Kl, Vl, relb, At0, At1);

    // phase-2: A=Wo^T (2048/256=8 row-blocks), B=att (4096/256=16)
    GArgs g2 = {};
    g2.A[0] = Wto; g2.A[1] = Wto;
    g2.B[0] = At0; g2.B[1] = At1;
    g2.bias[0] = bo; g2.bias[1] = bo;
    gemm8p<1><<<dim3(16, 8, 2), 512, 0, stream>>>(g2, out);
}